// Round 1
// baseline (406.511 us; speedup 1.0000x reference)
//
#include <hip/hip_runtime.h>

#define NODES 16384
#define NF 64
#define NBLK 128          // nodes per workgroup
#define SROW 72           // shorts per staged row (64 data + 8 pad) = 144 B
#define SROWS 270         // 255 real rows + padded-tile slack
#define TROW 72           // shorts per t-buffer row
#define BATCH 32

typedef __attribute__((ext_vector_type(8))) short short8;
typedef __attribute__((ext_vector_type(4))) short shortx4;
typedef __attribute__((ext_vector_type(4))) float floatx4;

__device__ __forceinline__ short f2bf(float f) {
    unsigned u = __float_as_uint(f);
    u += 0x7fffu + ((u >> 16) & 1u);          // RTNE (inputs finite)
    return (short)(u >> 16);
}
__device__ __forceinline__ float bf2f(short s) {
    return __uint_as_float(((unsigned)(unsigned short)s) << 16);
}
// Load 8 consecutive fp32 of W and convert to a bf16 B-fragment.
// W[k][o][i] is row-major in i, which IS the B^T layout the MFMA B operand wants.
__device__ __forceinline__ short8 loadW8(const float* p) {
    floatx4 a = *(const floatx4*)(p);
    floatx4 b = *(const floatx4*)(p + 4);
    short8 r;
    r[0]=f2bf(a[0]); r[1]=f2bf(a[1]); r[2]=f2bf(a[2]); r[3]=f2bf(a[3]);
    r[4]=f2bf(b[0]); r[5]=f2bf(b[1]); r[6]=f2bf(b[2]); r[7]=f2bf(b[3]);
    return r;
}

__global__ __launch_bounds__(256, 2)
void heaplin_kernel(const float* __restrict__ x, const float* __restrict__ W,
                    const float* __restrict__ bias, float* __restrict__ out)
{
    __shared__ short stage[SROWS * SROW];    // 38,880 B  bf16 A-rows
    __shared__ short tbuf[127 * TROW];       // 18,288 B  bf16 ancestor results t1..t7
    __shared__ float farpart[4 * 64];        //  1,024 B  partial far-ancestor sums

    const int tid  = threadIdx.x;
    const int lane = tid & 63;
    const int wave = tid >> 6;
    const int lr = lane & 15;                // MFMA row/col selector
    const int lq = lane >> 4;                // MFMA quad
    const int nblk = blockIdx.x;
    const int b    = blockIdx.y;
    const float* xb = x + (size_t)b * NODES * NF;
    float* ob = out + (size_t)b * NODES * NF;
    const floatx4 zero4 = {0.f, 0.f, 0.f, 0.f};

    if (nblk == 0) {
        // ---------- block-0 path: nodes 0..127 span levels 0..7 (masked) ----------
        float* cumB = (float*)tbuf;          // 15*64 fp32 bias prefix sums
        if (tid < 64) {
            float run = 0.f;
            for (int k = 0; k < 15; ++k) { run += bias[k * 64 + tid]; cumB[k * 64 + tid] = run; }
        }
        floatx4 accE[8];
        #pragma unroll
        for (int t8 = 0; t8 < 8; ++t8) accE[t8] = zero4;

        for (int k = 0; k < 8; ++k) {
            __syncthreads();                 // protects stage reuse (and cumB once)
            #pragma unroll
            for (int i = 0; i < 8; ++i) {    // 2048 staging jobs: row j = x[j>>k] or 0
                int job = tid + i * 256;
                int r = job >> 4, c4 = job & 15;
                bool valid = (k == 0) || (r >= (1 << (k - 1)));   // level(r) >= k
                floatx4 vv = zero4;
                if (valid) vv = *(const floatx4*)(xb + (r >> k) * NF + c4 * 4);
                shortx4 s4;
                s4[0]=f2bf(vv[0]); s4[1]=f2bf(vv[1]); s4[2]=f2bf(vv[2]); s4[3]=f2bf(vv[3]);
                *(shortx4*)(stage + r * SROW + c4 * 4) = s4;
            }
            __syncthreads();
            #pragma unroll
            for (int t8 = 0; t8 < 8; ++t8) {
                int mt = 2 * wave + (t8 & 1);
                int nt = t8 >> 1;
                int arow = mt * 16 + lr;
                const float* wr = W + k * 4096 + (nt * 16 + lr) * 64 + lq * 8;
                short8 b0 = loadW8(wr);
                short8 b1 = loadW8(wr + 32);
                short8 a0 = *(const short8*)(stage + arow * SROW + lq * 8);
                short8 a1 = *(const short8*)(stage + arow * SROW + 32 + lq * 8);
                accE[t8] = __builtin_amdgcn_mfma_f32_16x16x32_bf16(a0, b0, accE[t8], 0, 0, 0);
                accE[t8] = __builtin_amdgcn_mfma_f32_16x16x32_bf16(a1, b1, accE[t8], 0, 0, 0);
            }
        }
        #pragma unroll
        for (int t8 = 0; t8 < 8; ++t8) {
            int mt = 2 * wave + (t8 & 1);
            int nt = t8 >> 1;
            int c = nt * 16 + lr;
            #pragma unroll
            for (int rg = 0; rg < 4; ++rg) {
                int j = mt * 16 + lq * 4 + rg;
                int lvl = (j == 0) ? 0 : (32 - __clz(j));
                ob[(size_t)j * NF + c] = accE[t8][rg] + cumB[lvl * 64 + c];
            }
        }
        return;
    }

    // ---------- main path: block [n0, n0+128), uniform level L ----------
    const int n0 = nblk * NBLK;
    const int L  = 32 - __clz(n0);           // bit_length(n0), 8..14

    // Phase A: stage 128 own rows + 127 ancestor rows (k=1..7) as bf16.
    // Staged row r>=128 belongs to level k = 8 - bit_length(255-r); region base 256-(256>>k).
    floatx4 v[16];
    #pragma unroll
    for (int i = 0; i < 16; ++i) {
        int job = tid + i * 256;             // 4096 jobs (row 255 = dup slack)
        int r = job >> 4, c4 = job & 15;
        int node;
        if (r < 128)        node = n0 + r;
        else if (r >= 254)  node = n0 >> 7;
        else { int k = __clz(255 - r) - 24; node = (n0 >> k) + r - (256 - (256 >> k)); }
        v[i] = *(const floatx4*)(xb + (size_t)node * NF + c4 * 4);
    }
    #pragma unroll
    for (int i = 0; i < 16; ++i) {
        int job = tid + i * 256;
        int r = job >> 4, c4 = job & 15;
        shortx4 s4;
        s4[0]=f2bf(v[i][0]); s4[1]=f2bf(v[i][1]); s4[2]=f2bf(v[i][2]); s4[3]=f2bf(v[i][3]);
        *(shortx4*)(stage + r * SROW + c4 * 4) = s4;
    }
    __syncthreads();

    // Phase C: ancestor MFMAs (k=1..7) -> tbuf. 11 M-tiles x 4 N-tiles = 44 jobs, 11/wave.
    for (int jj = 0; jj < 11; ++jj) {
        int job = wave + jj * 4;
        int idx = job % 11;
        int nt  = job / 11;
        int k, mt;
        if (idx < 4)      { k = 1; mt = idx; }
        else if (idx < 6) { k = 2; mt = idx - 4; }
        else if (idx < 7) { k = 3; mt = 0; }
        else              { k = idx - 3; mt = 0; }      // k = 4..7, padded tiles
        int sbase = 256 - (256 >> k);
        int arow = sbase + mt * 16 + lr;
        const float* wr = W + k * 4096 + (nt * 16 + lr) * 64 + lq * 8;
        short8 b0 = loadW8(wr);
        short8 b1 = loadW8(wr + 32);
        short8 a0 = *(const short8*)(stage + arow * SROW + lq * 8);
        short8 a1 = *(const short8*)(stage + arow * SROW + 32 + lq * 8);
        floatx4 acc = zero4;
        acc = __builtin_amdgcn_mfma_f32_16x16x32_bf16(a0, b0, acc, 0, 0, 0);
        acc = __builtin_amdgcn_mfma_f32_16x16x32_bf16(a1, b1, acc, 0, 0, 0);
        int tb = 128 - (256 >> k);           // t-region base row: t1@0,t2@64,t3@96,...,t7@126
        int nvalid = 128 >> k;
        #pragma unroll
        for (int rg = 0; rg < 4; ++rg) {
            int m = mt * 16 + lq * 4 + rg;
            if (m < nvalid) tbuf[(tb + m) * TROW + nt * 16 + lr] = f2bf(acc[rg]);
        }
    }

    // Phase B: far ancestors (k=8..L, whole block shares one ancestor chain) + bias prefix.
    {
        float p = 0.f;
        const int q = wave, o = lane;
        for (int k = 8; k <= L; ++k) {
            const float* xa = xb + (size_t)(n0 >> k) * NF + q * 16;
            const float* wr = W + k * 4096 + o * 64 + q * 16;
            #pragma unroll
            for (int i = 0; i < 4; ++i) {
                floatx4 wv = *(const floatx4*)(wr + i * 4);
                floatx4 xv = *(const floatx4*)(xa + i * 4);
                p += wv[0]*xv[0] + wv[1]*xv[1] + wv[2]*xv[2] + wv[3]*xv[3];
            }
        }
        if (q == 0) for (int k = 0; k <= L; ++k) p += bias[k * 64 + o];
        farpart[q * 64 + o] = p;
    }
    __syncthreads();

    // Phase E: k=0 MFMAs, accumulators stay in registers (C-layout == output rows).
    floatx4 accE[8];
    #pragma unroll
    for (int t8 = 0; t8 < 8; ++t8) {
        int mt = 2 * wave + (t8 & 1);
        int nt = t8 >> 1;
        int arow = mt * 16 + lr;
        const float* wr = W + (nt * 16 + lr) * 64 + lq * 8;
        short8 b0 = loadW8(wr);
        short8 b1 = loadW8(wr + 32);
        short8 a0 = *(const short8*)(stage + arow * SROW + lq * 8);
        short8 a1 = *(const short8*)(stage + arow * SROW + 32 + lq * 8);
        floatx4 acc = zero4;
        acc = __builtin_amdgcn_mfma_f32_16x16x32_bf16(a0, b0, acc, 0, 0, 0);
        acc = __builtin_amdgcn_mfma_f32_16x16x32_bf16(a1, b1, acc, 0, 0, 0);
        accE[t8] = acc;
    }

    // Phase D: fold t2..t7 + far + bias into t1, so epilogue needs one gather.
    {
        int m  = tid >> 2;                   // 0..63
        int c0 = (tid & 3) * 16;
        float e[16];
        #pragma unroll
        for (int i = 0; i < 16; ++i) {
            int c = c0 + i;
            e[i] = bf2f(tbuf[ m              * TROW + c])
                 + bf2f(tbuf[(64  + (m >> 1)) * TROW + c])
                 + bf2f(tbuf[(96  + (m >> 2)) * TROW + c])
                 + bf2f(tbuf[(112 + (m >> 3)) * TROW + c])
                 + bf2f(tbuf[(120 + (m >> 4)) * TROW + c])
                 + bf2f(tbuf[(124 + (m >> 5)) * TROW + c])
                 + bf2f(tbuf[126              * TROW + c])
                 + farpart[c] + farpart[64 + c] + farpart[128 + c] + farpart[192 + c];
        }
        #pragma unroll
        for (int i = 0; i < 16; ++i) tbuf[m * TROW + c0 + i] = f2bf(e[i]);
    }
    __syncthreads();

    // Phase F: out[j] = k0-MFMA + u1[j>>1], fp32 store.
    #pragma unroll
    for (int t8 = 0; t8 < 8; ++t8) {
        int mt = 2 * wave + (t8 & 1);
        int nt = t8 >> 1;
        int c = nt * 16 + lr;
        #pragma unroll
        for (int rg = 0; rg < 4; ++rg) {
            int j = mt * 16 + lq * 4 + rg;
            float val = accE[t8][rg] + bf2f(tbuf[(j >> 1) * TROW + c]);
            ob[(size_t)(n0 + j) * NF + c] = val;
        }
    }
}

extern "C" void kernel_launch(void* const* d_in, const int* in_sizes, int n_in,
                              void* d_out, int out_size, void* d_ws, size_t ws_size,
                              hipStream_t stream) {
    const float* x  = (const float*)d_in[0];   // [32][16384][64]
    const float* W  = (const float*)d_in[1];   // [15][64][64]
    const float* bs = (const float*)d_in[2];   // [15][64]
    float* out = (float*)d_out;                // [32][16384][64]
    dim3 grid(NODES / NBLK, BATCH);
    heaplin_kernel<<<grid, 256, 0, stream>>>(x, W, bs, out);
}

// Round 2
// 392.703 us; speedup vs baseline: 1.0352x; 1.0352x over previous
//
#include <hip/hip_runtime.h>

#define NODES 16384
#define NF 64
#define NBLK 128          // nodes per workgroup
#define SROW 72           // shorts per staged row (64 data + 8 pad) = 144 B
#define SROWS 270         // 255 real rows + padded-tile slack
#define TROW 72           // shorts per t-buffer row
#define BATCH 32

typedef __attribute__((ext_vector_type(8))) short short8;
typedef __attribute__((ext_vector_type(4))) short shortx4;
typedef __attribute__((ext_vector_type(4))) float floatx4;

__device__ __forceinline__ short f2bf(float f) {
    unsigned u = __float_as_uint(f);
    u += 0x7fffu + ((u >> 16) & 1u);          // RTNE (inputs finite)
    return (short)(u >> 16);
}
__device__ __forceinline__ float bf2f(short s) {
    return __uint_as_float(((unsigned)(unsigned short)s) << 16);
}
// Load 8 consecutive fp32 of W and convert to a bf16 B-fragment.
// W[k][o][i] is row-major in i, which IS the B^T layout the MFMA B operand wants.
__device__ __forceinline__ short8 loadW8(const float* p) {
    floatx4 a = *(const floatx4*)(p);
    floatx4 b = *(const floatx4*)(p + 4);
    short8 r;
    r[0]=f2bf(a[0]); r[1]=f2bf(a[1]); r[2]=f2bf(a[2]); r[3]=f2bf(a[3]);
    r[4]=f2bf(b[0]); r[5]=f2bf(b[1]); r[6]=f2bf(b[2]); r[7]=f2bf(b[3]);
    return r;
}

// LDS budget: stage 38,880 B + farpart 1,024 B ≈ 39.9 KB -> 4 blocks/CU
// (previous version had a separate 18.3 KB tbuf -> 58.4 KB -> only 2 blocks/CU,
//  19% occupancy, latency-bound at 258 us). tbuf now ALIASES stage rows 0..127,
// legal because phase E (reads rows 0..127) runs before phase C (writes tbuf,
// reads only rows 128..269).
__global__ __launch_bounds__(256, 4)
void heaplin_kernel(const float* __restrict__ x, const float* __restrict__ W,
                    const float* __restrict__ bias, float* __restrict__ out)
{
    __shared__ short stage[SROWS * SROW];    // 38,880 B  bf16 A-rows
    __shared__ float farpart[4 * 64];        //  1,024 B  partial far-ancestor sums
    short* tbuf = stage;                     // rows 0..127 reused after phase E
    float* cumB = (float*)(stage + 128 * SROW);  // block-0 only; rows >=128 safe there

    const int tid  = threadIdx.x;
    const int lane = tid & 63;
    const int wave = tid >> 6;
    const int lr = lane & 15;                // MFMA row/col selector
    const int lq = lane >> 4;                // MFMA quad
    const int nblk = blockIdx.x;
    const int b    = blockIdx.y;
    const float* xb = x + (size_t)b * NODES * NF;
    float* ob = out + (size_t)b * NODES * NF;
    const floatx4 zero4 = {0.f, 0.f, 0.f, 0.f};

    if (nblk == 0) {
        // ---------- block-0 path: nodes 0..127 span levels 0..7 (masked) ----------
        // cumB lives in stage rows >=128; block-0 staging only writes rows 0..127.
        if (tid < 64) {
            float run = 0.f;
            for (int k = 0; k < 15; ++k) { run += bias[k * 64 + tid]; cumB[k * 64 + tid] = run; }
        }
        floatx4 accE[8];
        #pragma unroll
        for (int t8 = 0; t8 < 8; ++t8) accE[t8] = zero4;

        for (int k = 0; k < 8; ++k) {
            __syncthreads();                 // protects stage reuse across k
            #pragma unroll
            for (int i = 0; i < 8; ++i) {    // 2048 staging jobs: row j = x[j>>k] or 0
                int job = tid + i * 256;
                int r = job >> 4, c4 = job & 15;
                bool valid = (k == 0) || (r >= (1 << (k - 1)));   // level(r) >= k
                floatx4 vv = zero4;
                if (valid) vv = *(const floatx4*)(xb + (r >> k) * NF + c4 * 4);
                shortx4 s4;
                s4[0]=f2bf(vv[0]); s4[1]=f2bf(vv[1]); s4[2]=f2bf(vv[2]); s4[3]=f2bf(vv[3]);
                *(shortx4*)(stage + r * SROW + c4 * 4) = s4;
            }
            __syncthreads();
            #pragma unroll
            for (int t8 = 0; t8 < 8; ++t8) {
                int mt = 2 * wave + (t8 & 1);
                int nt = t8 >> 1;
                int arow = mt * 16 + lr;
                const float* wr = W + k * 4096 + (nt * 16 + lr) * 64 + lq * 8;
                short8 b0 = loadW8(wr);
                short8 b1 = loadW8(wr + 32);
                short8 a0 = *(const short8*)(stage + arow * SROW + lq * 8);
                short8 a1 = *(const short8*)(stage + arow * SROW + 32 + lq * 8);
                accE[t8] = __builtin_amdgcn_mfma_f32_16x16x32_bf16(a0, b0, accE[t8], 0, 0, 0);
                accE[t8] = __builtin_amdgcn_mfma_f32_16x16x32_bf16(a1, b1, accE[t8], 0, 0, 0);
            }
        }
        #pragma unroll
        for (int t8 = 0; t8 < 8; ++t8) {
            int mt = 2 * wave + (t8 & 1);
            int nt = t8 >> 1;
            int c = nt * 16 + lr;
            #pragma unroll
            for (int rg = 0; rg < 4; ++rg) {
                int j = mt * 16 + lq * 4 + rg;
                int lvl = (j == 0) ? 0 : (32 - __clz(j));
                ob[(size_t)j * NF + c] = accE[t8][rg] + cumB[lvl * 64 + c];
            }
        }
        return;
    }

    // ---------- main path: block [n0, n0+128), uniform level L ----------
    const int n0 = nblk * NBLK;
    const int L  = 32 - __clz(n0);           // bit_length(n0), 8..14

    // Phase A: stage 128 own rows + 127 ancestor rows (k=1..7) as bf16.
    // Staged row r>=128 belongs to level k = 8 - bit_length(255-r); region base 256-(256>>k).
    floatx4 v[16];
    #pragma unroll
    for (int i = 0; i < 16; ++i) {
        int job = tid + i * 256;             // 4096 jobs (row 255 = dup slack)
        int r = job >> 4, c4 = job & 15;
        int node;
        if (r < 128)        node = n0 + r;
        else if (r >= 254)  node = n0 >> 7;
        else { int k = __clz(255 - r) - 24; node = (n0 >> k) + r - (256 - (256 >> k)); }
        v[i] = *(const floatx4*)(xb + (size_t)node * NF + c4 * 4);
    }
    #pragma unroll
    for (int i = 0; i < 16; ++i) {
        int job = tid + i * 256;
        int r = job >> 4, c4 = job & 15;
        shortx4 s4;
        s4[0]=f2bf(v[i][0]); s4[1]=f2bf(v[i][1]); s4[2]=f2bf(v[i][2]); s4[3]=f2bf(v[i][3]);
        *(shortx4*)(stage + r * SROW + c4 * 4) = s4;
    }
    __syncthreads();

    // Phase E: k=0 MFMAs FIRST, accumulators stay in registers (C-layout == output rows).
    // Must precede phase C, which overwrites stage rows 0..127 (tbuf alias).
    floatx4 accE[8];
    #pragma unroll
    for (int t8 = 0; t8 < 8; ++t8) {
        int mt = 2 * wave + (t8 & 1);
        int nt = t8 >> 1;
        int arow = mt * 16 + lr;
        const float* wr = W + (nt * 16 + lr) * 64 + lq * 8;
        short8 b0 = loadW8(wr);
        short8 b1 = loadW8(wr + 32);
        short8 a0 = *(const short8*)(stage + arow * SROW + lq * 8);
        short8 a1 = *(const short8*)(stage + arow * SROW + 32 + lq * 8);
        floatx4 acc = zero4;
        acc = __builtin_amdgcn_mfma_f32_16x16x32_bf16(a0, b0, acc, 0, 0, 0);
        acc = __builtin_amdgcn_mfma_f32_16x16x32_bf16(a1, b1, acc, 0, 0, 0);
        accE[t8] = acc;
    }

    // Phase B: far ancestors (k=8..L, whole block shares one ancestor chain) + bias prefix.
    {
        float p = 0.f;
        const int q = wave, o = lane;
        for (int k = 8; k <= L; ++k) {
            const float* xa = xb + (size_t)(n0 >> k) * NF + q * 16;
            const float* wr = W + k * 4096 + o * 64 + q * 16;
            #pragma unroll
            for (int i = 0; i < 4; ++i) {
                floatx4 wv = *(const floatx4*)(wr + i * 4);
                floatx4 xv = *(const floatx4*)(xa + i * 4);
                p += wv[0]*xv[0] + wv[1]*xv[1] + wv[2]*xv[2] + wv[3]*xv[3];
            }
        }
        if (q == 0) for (int k = 0; k <= L; ++k) p += bias[k * 64 + o];
        farpart[q * 64 + o] = p;
    }
    __syncthreads();    // all phase-E reads of rows 0..127 done; tbuf writes may begin

    // Phase C: ancestor MFMAs (k=1..7) -> tbuf (= stage rows 0..127).
    // Reads only stage rows 128..269. 11 M-tiles x 4 N-tiles = 44 jobs, 11/wave.
    for (int jj = 0; jj < 11; ++jj) {
        int job = wave + jj * 4;
        int idx = job % 11;
        int nt  = job / 11;
        int k, mt;
        if (idx < 4)      { k = 1; mt = idx; }
        else if (idx < 6) { k = 2; mt = idx - 4; }
        else if (idx < 7) { k = 3; mt = 0; }
        else              { k = idx - 3; mt = 0; }      // k = 4..7, padded tiles
        int sbase = 256 - (256 >> k);
        int arow = sbase + mt * 16 + lr;
        const float* wr = W + k * 4096 + (nt * 16 + lr) * 64 + lq * 8;
        short8 b0 = loadW8(wr);
        short8 b1 = loadW8(wr + 32);
        short8 a0 = *(const short8*)(stage + arow * SROW + lq * 8);
        short8 a1 = *(const short8*)(stage + arow * SROW + 32 + lq * 8);
        floatx4 acc = zero4;
        acc = __builtin_amdgcn_mfma_f32_16x16x32_bf16(a0, b0, acc, 0, 0, 0);
        acc = __builtin_amdgcn_mfma_f32_16x16x32_bf16(a1, b1, acc, 0, 0, 0);
        int tb = 128 - (256 >> k);           // t-region base row: t1@0,t2@64,t3@96,...,t7@126
        int nvalid = 128 >> k;
        #pragma unroll
        for (int rg = 0; rg < 4; ++rg) {
            int m = mt * 16 + lq * 4 + rg;
            if (m < nvalid) tbuf[(tb + m) * TROW + nt * 16 + lr] = f2bf(acc[rg]);
        }
    }
    __syncthreads();

    // Phase D: fold t2..t7 + far + bias into t1, so epilogue needs one gather.
    {
        int m  = tid >> 2;                   // 0..63
        int c0 = (tid & 3) * 16;
        float e[16];
        #pragma unroll
        for (int i = 0; i < 16; ++i) {
            int c = c0 + i;
            e[i] = bf2f(tbuf[ m              * TROW + c])
                 + bf2f(tbuf[(64  + (m >> 1)) * TROW + c])
                 + bf2f(tbuf[(96  + (m >> 2)) * TROW + c])
                 + bf2f(tbuf[(112 + (m >> 3)) * TROW + c])
                 + bf2f(tbuf[(120 + (m >> 4)) * TROW + c])
                 + bf2f(tbuf[(124 + (m >> 5)) * TROW + c])
                 + bf2f(tbuf[126              * TROW + c])
                 + farpart[c] + farpart[64 + c] + farpart[128 + c] + farpart[192 + c];
        }
        #pragma unroll
        for (int i = 0; i < 16; ++i) tbuf[m * TROW + c0 + i] = f2bf(e[i]);
    }
    __syncthreads();

    // Phase F: out[j] = k0-MFMA + u1[j>>1], fp32 store.
    #pragma unroll
    for (int t8 = 0; t8 < 8; ++t8) {
        int mt = 2 * wave + (t8 & 1);
        int nt = t8 >> 1;
        int c = nt * 16 + lr;
        #pragma unroll
        for (int rg = 0; rg < 4; ++rg) {
            int j = mt * 16 + lq * 4 + rg;
            float val = accE[t8][rg] + bf2f(tbuf[(j >> 1) * TROW + c]);
            ob[(size_t)(n0 + j) * NF + c] = val;
        }
    }
}

extern "C" void kernel_launch(void* const* d_in, const int* in_sizes, int n_in,
                              void* d_out, int out_size, void* d_ws, size_t ws_size,
                              hipStream_t stream) {
    const float* x  = (const float*)d_in[0];   // [32][16384][64]
    const float* W  = (const float*)d_in[1];   // [15][64][64]
    const float* bs = (const float*)d_in[2];   // [15][64]
    float* out = (float*)d_out;                // [32][16384][64]
    dim3 grid(NODES / NBLK, BATCH);
    heaplin_kernel<<<grid, 256, 0, stream>>>(x, W, bs, out);
}

// Round 3
// 359.698 us; speedup vs baseline: 1.1301x; 1.0918x over previous
//
#include <hip/hip_runtime.h>

#define NODES 16384
#define NF 64
#define NBLK 128          // nodes per workgroup (main kernel)
#define TROW 72           // shorts per tbuf/stage row (64 data + 8 pad) = 144 B
#define BATCH 32

// ws layout (bytes): xswz bf16 @0 (64 MiB), wbf bf16 @67108864 (122,880),
// bprefix fp32 @67231744 (3,840). Total 67,235,584.
#define WS_XSWZ_OFF   0ull
#define WS_WBF_OFF    67108864ull
#define WS_BPRE_OFF   67231744ull
#define WS_NEEDED     67235584ull

typedef __attribute__((ext_vector_type(8))) short short8;
typedef __attribute__((ext_vector_type(4))) short shortx4;
typedef __attribute__((ext_vector_type(4))) float floatx4;

__device__ __forceinline__ short f2bf(float f) {
    unsigned u = __float_as_uint(f);
    u += 0x7fffu + ((u >> 16) & 1u);          // RTNE (inputs finite)
    return (short)(u >> 16);
}
__device__ __forceinline__ float bf2f(short s) {
    return __uint_as_float(((unsigned)(unsigned short)s) << 16);
}
__device__ __forceinline__ short8 cvt8(floatx4 a, floatx4 c) {
    short8 r;
    r[0]=f2bf(a[0]); r[1]=f2bf(a[1]); r[2]=f2bf(a[2]); r[3]=f2bf(a[3]);
    r[4]=f2bf(c[0]); r[5]=f2bf(c[1]); r[6]=f2bf(c[2]); r[7]=f2bf(c[3]);
    return r;
}

// ---------------------------------------------------------------------------
// Prep kernel: one-time conversions.
//  blocks [0,16384):      x fp32 -> bf16, swizzled to MFMA A-fragment tile order.
//    16-row tile, position p = chunk*16 + row_in_tile (chunk = 8 shorts of k-dim).
//    xswz[g*8..g*8+7] with g = tile_global*128 + p  -> writes perfectly coalesced.
//  blocks [16384,16414):  W fp32 -> bf16 (same [k][o][i] layout).
//  block 16414:           bias prefix sums (fp32).
// ---------------------------------------------------------------------------
__global__ __launch_bounds__(256)
void heaplin_prep(const float* __restrict__ x, const float* __restrict__ W,
                  const float* __restrict__ bias,
                  short* __restrict__ xswz, short* __restrict__ wbf,
                  float* __restrict__ bpre)
{
    const int blk = blockIdx.x;
    const int tid = threadIdx.x;
    if (blk < 16384) {
        int g  = blk * 256 + tid;            // [0, 4,194,304)
        int p  = g & 127;
        int tg = g >> 7;                     // b*1024 + tile
        const float* src = x + ((size_t)(tg << 4) + (p & 15)) * NF + (p >> 4) * 8;
        floatx4 a = *(const floatx4*)src;
        floatx4 c = *(const floatx4*)(src + 4);
        *(short8*)(xswz + (size_t)g * 8) = cvt8(a, c);
    } else if (blk < 16414) {
        int e = (blk - 16384) * 2048 + tid * 8;   // [0, 61440)
        floatx4 a = *(const floatx4*)(W + e);
        floatx4 c = *(const floatx4*)(W + e + 4);
        *(short8*)(wbf + e) = cvt8(a, c);
    } else {
        if (tid < 64) {
            float run = 0.f;
            for (int k = 0; k < 15; ++k) { run += bias[k * 64 + tid]; bpre[k * 64 + tid] = run; }
        }
    }
}

// ---------------------------------------------------------------------------
// Main kernel. LDS = 18,432 + 1,024 = 19.5 KB -> 8 blocks/CU.
// A-fragments load directly from swizzled global (coalesced 16 B/lane), W from
// pre-converted bf16 -> zero conversion VALU on all MFMA paths, no staging LDS.
// ---------------------------------------------------------------------------
__global__ __launch_bounds__(256, 4)
void heaplin_main(const float* __restrict__ x, const float* __restrict__ W,
                  const short* __restrict__ xswz, const short* __restrict__ wbf,
                  const float* __restrict__ bpre, float* __restrict__ out)
{
    __shared__ short tbuf[128 * TROW];       // main: t1..t7 rows 0..126; block0: stage rows 0..127
    __shared__ float farpart[4 * 64];

    const int tid  = threadIdx.x;
    const int lane = tid & 63;
    const int wave = tid >> 6;
    const int lr = lane & 15;
    const int lq = lane >> 4;
    const int nblk = blockIdx.x;
    const int b    = blockIdx.y;
    const float* xb = x + (size_t)b * NODES * NF;
    const short* xsb = xswz + (size_t)b * NODES * NF;
    float* ob = out + (size_t)b * NODES * NF;
    const floatx4 zero4 = {0.f, 0.f, 0.f, 0.f};

    if (nblk == 0) {
        // ---------- block-0 path: nodes 0..127 span levels 0..7 (masked) ----------
        floatx4 accE[8];
        #pragma unroll
        for (int t8 = 0; t8 < 8; ++t8) accE[t8] = zero4;

        for (int k = 0; k < 8; ++k) {
            __syncthreads();
            #pragma unroll
            for (int i = 0; i < 8; ++i) {    // 2048 jobs: stage row j = x[j>>k] or 0
                int job = tid + i * 256;
                int r = job >> 4, c4 = job & 15;
                bool valid = (k == 0) || (r >= (1 << (k - 1)));
                floatx4 vv = zero4;
                if (valid) vv = *(const floatx4*)(xb + (r >> k) * NF + c4 * 4);
                shortx4 s4;
                s4[0]=f2bf(vv[0]); s4[1]=f2bf(vv[1]); s4[2]=f2bf(vv[2]); s4[3]=f2bf(vv[3]);
                *(shortx4*)(tbuf + r * TROW + c4 * 4) = s4;
            }
            __syncthreads();
            #pragma unroll
            for (int t8 = 0; t8 < 8; ++t8) {
                int mt = 2 * wave + (t8 & 1);
                int nt = t8 >> 1;
                int arow = mt * 16 + lr;
                const short* wp = wbf + k * 4096 + (nt * 16 + lr) * 64 + lq * 8;
                short8 b0 = *(const short8*)wp;
                short8 b1 = *(const short8*)(wp + 32);
                short8 a0 = *(const short8*)(tbuf + arow * TROW + lq * 8);
                short8 a1 = *(const short8*)(tbuf + arow * TROW + 32 + lq * 8);
                accE[t8] = __builtin_amdgcn_mfma_f32_16x16x32_bf16(a0, b0, accE[t8], 0, 0, 0);
                accE[t8] = __builtin_amdgcn_mfma_f32_16x16x32_bf16(a1, b1, accE[t8], 0, 0, 0);
            }
        }
        #pragma unroll
        for (int t8 = 0; t8 < 8; ++t8) {
            int mt = 2 * wave + (t8 & 1);
            int nt = t8 >> 1;
            int c = nt * 16 + lr;
            #pragma unroll
            for (int rg = 0; rg < 4; ++rg) {
                int j = mt * 16 + lq * 4 + rg;
                int lvl = (j == 0) ? 0 : (32 - __clz(j));
                ob[(size_t)j * NF + c] = accE[t8][rg] + bpre[lvl * 64 + c];
            }
        }
        return;
    }

    // ---------- main path: block [n0, n0+128), uniform level L ----------
    const int n0 = nblk * NBLK;
    const int L  = 32 - __clz(n0);           // 8..14

    // Phase E: k=0 MFMAs straight from swizzled global; acc stays in registers.
    floatx4 accE[8];
    const short* xtile0 = xsb + (size_t)(n0 >> 4) * 1024;   // tile = 1024 shorts
    #pragma unroll
    for (int t8 = 0; t8 < 8; ++t8) {
        int mt = 2 * wave + (t8 & 1);
        int nt = t8 >> 1;
        const short* ap = xtile0 + mt * 1024 + lane * 8;
        short8 a0 = *(const short8*)ap;
        short8 a1 = *(const short8*)(ap + 512);
        const short* wp = wbf + (nt * 16 + lr) * 64 + lq * 8;
        short8 b0 = *(const short8*)wp;
        short8 b1 = *(const short8*)(wp + 32);
        floatx4 acc = zero4;
        acc = __builtin_amdgcn_mfma_f32_16x16x32_bf16(a0, b0, acc, 0, 0, 0);
        acc = __builtin_amdgcn_mfma_f32_16x16x32_bf16(a1, b1, acc, 0, 0, 0);
        accE[t8] = acc;
    }

    // Phase B: far ancestors (k=8..L, one shared chain) + bias prefix (precomputed).
    {
        float p = 0.f;
        const int q = wave, o = lane;
        for (int k = 8; k <= L; ++k) {
            const float* xa = xb + (size_t)(n0 >> k) * NF + q * 16;
            const float* wr = W + k * 4096 + o * 64 + q * 16;
            #pragma unroll
            for (int i = 0; i < 4; ++i) {
                floatx4 wv = *(const floatx4*)(wr + i * 4);
                floatx4 xv = *(const floatx4*)(xa + i * 4);
                p += wv[0]*xv[0] + wv[1]*xv[1] + wv[2]*xv[2] + wv[3]*xv[3];
            }
        }
        if (q == 0) p += bpre[L * 64 + o];
        farpart[q * 64 + o] = p;
    }

    // Phase C: ancestor MFMAs (k=1..7) from swizzled global -> tbuf.
    // 44 jobs = 11 tile-jobs x 4 N-tiles; job = wave*11 + jj; nt = job&3, idx = job>>2.
    for (int jj = 0; jj < 11; ++jj) {
        int job = wave * 11 + jj;
        int idx = job >> 2;
        int nt  = job & 3;
        int k, mt;
        if (idx < 4)       { k = 1; mt = idx; }
        else if (idx < 6)  { k = 2; mt = idx - 4; }
        else if (idx == 6) { k = 3; mt = 0; }
        else               { k = idx - 3; mt = 0; }     // k = 4..7
        int anc = n0 >> k;
        int T   = (anc >> 4) + mt;                      // 16-row tile index
        int off = anc & 15;                             // 0 for k<=3
        const short* ap = xsb + (size_t)T * 1024 + lane * 8;
        short8 a0 = *(const short8*)ap;
        short8 a1 = *(const short8*)(ap + 512);
        const short* wp = wbf + k * 4096 + (nt * 16 + lr) * 64 + lq * 8;
        short8 b0 = *(const short8*)wp;
        short8 b1 = *(const short8*)(wp + 32);
        floatx4 acc = zero4;
        acc = __builtin_amdgcn_mfma_f32_16x16x32_bf16(a0, b0, acc, 0, 0, 0);
        acc = __builtin_amdgcn_mfma_f32_16x16x32_bf16(a1, b1, acc, 0, 0, 0);
        int tb  = 128 - (256 >> k);         // region base: t1@0,t2@64,...,t7@126
        int cnt = 128 >> k;
        #pragma unroll
        for (int rg = 0; rg < 4; ++rg) {
            int m = lq * 4 + rg;            // row within tile
            if (k <= 3) {
                tbuf[(tb + mt * 16 + m) * TROW + nt * 16 + lr] = f2bf(acc[rg]);
            } else if (m >= off && m < off + cnt) {
                tbuf[(tb + m - off) * TROW + nt * 16 + lr] = f2bf(acc[rg]);
            }
        }
    }
    __syncthreads();

    // Phase D: fold t2..t7 + far + bias into t1 (u1), one gather in epilogue.
    {
        int m  = tid >> 2;                   // 0..63
        int c0 = (tid & 3) * 16;
        float e[16];
        #pragma unroll
        for (int i = 0; i < 16; ++i) {
            int c = c0 + i;
            e[i] = bf2f(tbuf[ m               * TROW + c])
                 + bf2f(tbuf[(64  + (m >> 1)) * TROW + c])
                 + bf2f(tbuf[(96  + (m >> 2)) * TROW + c])
                 + bf2f(tbuf[(112 + (m >> 3)) * TROW + c])
                 + bf2f(tbuf[(120 + (m >> 4)) * TROW + c])
                 + bf2f(tbuf[(124 + (m >> 5)) * TROW + c])
                 + bf2f(tbuf[126              * TROW + c])
                 + farpart[c] + farpart[64 + c] + farpart[128 + c] + farpart[192 + c];
        }
        #pragma unroll
        for (int i = 0; i < 16; ++i) tbuf[m * TROW + c0 + i] = f2bf(e[i]);
    }
    __syncthreads();

    // Phase F: out[j] = k0-MFMA + u1[j>>1], fp32 store.
    #pragma unroll
    for (int t8 = 0; t8 < 8; ++t8) {
        int mt = 2 * wave + (t8 & 1);
        int nt = t8 >> 1;
        int c = nt * 16 + lr;
        #pragma unroll
        for (int rg = 0; rg < 4; ++rg) {
            int j = mt * 16 + lq * 4 + rg;
            float val = accE[t8][rg] + bf2f(tbuf[(j >> 1) * TROW + c]);
            ob[(size_t)(n0 + j) * NF + c] = val;
        }
    }
}

// ---------------------------------------------------------------------------
// Fallback (R2 kernel, passing): used only if ws is too small for the bf16 scratch.
// ---------------------------------------------------------------------------
#define SROW 72
#define SROWS 270
__global__ __launch_bounds__(256, 4)
void heaplin_fallback(const float* __restrict__ x, const float* __restrict__ W,
                      const float* __restrict__ bias, float* __restrict__ out)
{
    __shared__ short stage[SROWS * SROW];
    __shared__ float farpart[4 * 64];
    short* tbuf = stage;
    float* cumB = (float*)(stage + 128 * SROW);

    const int tid  = threadIdx.x;
    const int lane = tid & 63;
    const int wave = tid >> 6;
    const int lr = lane & 15;
    const int lq = lane >> 4;
    const int nblk = blockIdx.x;
    const int b    = blockIdx.y;
    const float* xb = x + (size_t)b * NODES * NF;
    float* ob = out + (size_t)b * NODES * NF;
    const floatx4 zero4 = {0.f, 0.f, 0.f, 0.f};

    if (nblk == 0) {
        if (tid < 64) {
            float run = 0.f;
            for (int k = 0; k < 15; ++k) { run += bias[k * 64 + tid]; cumB[k * 64 + tid] = run; }
        }
        floatx4 accE[8];
        #pragma unroll
        for (int t8 = 0; t8 < 8; ++t8) accE[t8] = zero4;
        for (int k = 0; k < 8; ++k) {
            __syncthreads();
            #pragma unroll
            for (int i = 0; i < 8; ++i) {
                int job = tid + i * 256;
                int r = job >> 4, c4 = job & 15;
                bool valid = (k == 0) || (r >= (1 << (k - 1)));
                floatx4 vv = zero4;
                if (valid) vv = *(const floatx4*)(xb + (r >> k) * NF + c4 * 4);
                shortx4 s4;
                s4[0]=f2bf(vv[0]); s4[1]=f2bf(vv[1]); s4[2]=f2bf(vv[2]); s4[3]=f2bf(vv[3]);
                *(shortx4*)(stage + r * SROW + c4 * 4) = s4;
            }
            __syncthreads();
            #pragma unroll
            for (int t8 = 0; t8 < 8; ++t8) {
                int mt = 2 * wave + (t8 & 1);
                int nt = t8 >> 1;
                int arow = mt * 16 + lr;
                const float* wr = W + k * 4096 + (nt * 16 + lr) * 64 + lq * 8;
                floatx4 wa = *(const floatx4*)wr, wb2 = *(const floatx4*)(wr + 4);
                short8 b0 = cvt8(wa, wb2);
                floatx4 wc = *(const floatx4*)(wr + 32), wd = *(const floatx4*)(wr + 36);
                short8 b1 = cvt8(wc, wd);
                short8 a0 = *(const short8*)(stage + arow * SROW + lq * 8);
                short8 a1 = *(const short8*)(stage + arow * SROW + 32 + lq * 8);
                accE[t8] = __builtin_amdgcn_mfma_f32_16x16x32_bf16(a0, b0, accE[t8], 0, 0, 0);
                accE[t8] = __builtin_amdgcn_mfma_f32_16x16x32_bf16(a1, b1, accE[t8], 0, 0, 0);
            }
        }
        #pragma unroll
        for (int t8 = 0; t8 < 8; ++t8) {
            int mt = 2 * wave + (t8 & 1);
            int nt = t8 >> 1;
            int c = nt * 16 + lr;
            #pragma unroll
            for (int rg = 0; rg < 4; ++rg) {
                int j = mt * 16 + lq * 4 + rg;
                int lvl = (j == 0) ? 0 : (32 - __clz(j));
                ob[(size_t)j * NF + c] = accE[t8][rg] + cumB[lvl * 64 + c];
            }
        }
        return;
    }

    const int n0 = nblk * NBLK;
    const int L  = 32 - __clz(n0);
    floatx4 v[16];
    #pragma unroll
    for (int i = 0; i < 16; ++i) {
        int job = tid + i * 256;
        int r = job >> 4, c4 = job & 15;
        int node;
        if (r < 128)        node = n0 + r;
        else if (r >= 254)  node = n0 >> 7;
        else { int k = __clz(255 - r) - 24; node = (n0 >> k) + r - (256 - (256 >> k)); }
        v[i] = *(const floatx4*)(xb + (size_t)node * NF + c4 * 4);
    }
    #pragma unroll
    for (int i = 0; i < 16; ++i) {
        int job = tid + i * 256;
        int r = job >> 4, c4 = job & 15;
        shortx4 s4;
        s4[0]=f2bf(v[i][0]); s4[1]=f2bf(v[i][1]); s4[2]=f2bf(v[i][2]); s4[3]=f2bf(v[i][3]);
        *(shortx4*)(stage + r * SROW + c4 * 4) = s4;
    }
    __syncthreads();
    floatx4 accE[8];
    #pragma unroll
    for (int t8 = 0; t8 < 8; ++t8) {
        int mt = 2 * wave + (t8 & 1);
        int nt = t8 >> 1;
        int arow = mt * 16 + lr;
        const float* wr = W + (nt * 16 + lr) * 64 + lq * 8;
        floatx4 wa = *(const floatx4*)wr, wb2 = *(const floatx4*)(wr + 4);
        short8 b0 = cvt8(wa, wb2);
        floatx4 wc = *(const floatx4*)(wr + 32), wd = *(const floatx4*)(wr + 36);
        short8 b1 = cvt8(wc, wd);
        short8 a0 = *(const short8*)(stage + arow * SROW + lq * 8);
        short8 a1 = *(const short8*)(stage + arow * SROW + 32 + lq * 8);
        floatx4 acc = zero4;
        acc = __builtin_amdgcn_mfma_f32_16x16x32_bf16(a0, b0, acc, 0, 0, 0);
        acc = __builtin_amdgcn_mfma_f32_16x16x32_bf16(a1, b1, acc, 0, 0, 0);
        accE[t8] = acc;
    }
    {
        float p = 0.f;
        const int q = wave, o = lane;
        for (int k = 8; k <= L; ++k) {
            const float* xa = xb + (size_t)(n0 >> k) * NF + q * 16;
            const float* wr = W + k * 4096 + o * 64 + q * 16;
            #pragma unroll
            for (int i = 0; i < 4; ++i) {
                floatx4 wv = *(const floatx4*)(wr + i * 4);
                floatx4 xv = *(const floatx4*)(xa + i * 4);
                p += wv[0]*xv[0] + wv[1]*xv[1] + wv[2]*xv[2] + wv[3]*xv[3];
            }
        }
        if (q == 0) for (int k = 0; k <= L; ++k) p += bias[k * 64 + o];
        farpart[q * 64 + o] = p;
    }
    __syncthreads();
    for (int jj = 0; jj < 11; ++jj) {
        int job = wave + jj * 4;
        int idx = job % 11;
        int nt  = job / 11;
        int k, mt;
        if (idx < 4)      { k = 1; mt = idx; }
        else if (idx < 6) { k = 2; mt = idx - 4; }
        else if (idx < 7) { k = 3; mt = 0; }
        else              { k = idx - 3; mt = 0; }
        int sbase = 256 - (256 >> k);
        int arow = sbase + mt * 16 + lr;
        const float* wr = W + k * 4096 + (nt * 16 + lr) * 64 + lq * 8;
        floatx4 wa = *(const floatx4*)wr, wb2 = *(const floatx4*)(wr + 4);
        short8 b0 = cvt8(wa, wb2);
        floatx4 wc = *(const floatx4*)(wr + 32), wd = *(const floatx4*)(wr + 36);
        short8 b1 = cvt8(wc, wd);
        short8 a0 = *(const short8*)(stage + arow * SROW + lq * 8);
        short8 a1 = *(const short8*)(stage + arow * SROW + 32 + lq * 8);
        floatx4 acc = zero4;
        acc = __builtin_amdgcn_mfma_f32_16x16x32_bf16(a0, b0, acc, 0, 0, 0);
        acc = __builtin_amdgcn_mfma_f32_16x16x32_bf16(a1, b1, acc, 0, 0, 0);
        int tb = 128 - (256 >> k);
        int nvalid = 128 >> k;
        #pragma unroll
        for (int rg = 0; rg < 4; ++rg) {
            int m = mt * 16 + lq * 4 + rg;
            if (m < nvalid) tbuf[(tb + m) * TROW + nt * 16 + lr] = f2bf(acc[rg]);
        }
    }
    __syncthreads();
    {
        int m  = tid >> 2;
        int c0 = (tid & 3) * 16;
        float e[16];
        #pragma unroll
        for (int i = 0; i < 16; ++i) {
            int c = c0 + i;
            e[i] = bf2f(tbuf[ m               * TROW + c])
                 + bf2f(tbuf[(64  + (m >> 1)) * TROW + c])
                 + bf2f(tbuf[(96  + (m >> 2)) * TROW + c])
                 + bf2f(tbuf[(112 + (m >> 3)) * TROW + c])
                 + bf2f(tbuf[(120 + (m >> 4)) * TROW + c])
                 + bf2f(tbuf[(124 + (m >> 5)) * TROW + c])
                 + bf2f(tbuf[126              * TROW + c])
                 + farpart[c] + farpart[64 + c] + farpart[128 + c] + farpart[192 + c];
        }
        #pragma unroll
        for (int i = 0; i < 16; ++i) tbuf[m * TROW + c0 + i] = f2bf(e[i]);
    }
    __syncthreads();
    #pragma unroll
    for (int t8 = 0; t8 < 8; ++t8) {
        int mt = 2 * wave + (t8 & 1);
        int nt = t8 >> 1;
        int c = nt * 16 + lr;
        #pragma unroll
        for (int rg = 0; rg < 4; ++rg) {
            int j = mt * 16 + lq * 4 + rg;
            float val = accE[t8][rg] + bf2f(tbuf[(j >> 1) * TROW + c]);
            ob[(size_t)(n0 + j) * NF + c] = val;
        }
    }
}

extern "C" void kernel_launch(void* const* d_in, const int* in_sizes, int n_in,
                              void* d_out, int out_size, void* d_ws, size_t ws_size,
                              hipStream_t stream) {
    const float* x  = (const float*)d_in[0];   // [32][16384][64]
    const float* W  = (const float*)d_in[1];   // [15][64][64]
    const float* bs = (const float*)d_in[2];   // [15][64]
    float* out = (float*)d_out;                // [32][16384][64]
    dim3 grid(NODES / NBLK, BATCH);
    if (ws_size >= WS_NEEDED) {
        short* xswz = (short*)((char*)d_ws + WS_XSWZ_OFF);
        short* wbf  = (short*)((char*)d_ws + WS_WBF_OFF);
        float* bpre = (float*)((char*)d_ws + WS_BPRE_OFF);
        heaplin_prep<<<16415, 256, 0, stream>>>(x, W, bs, xswz, wbf, bpre);
        heaplin_main<<<grid, 256, 0, stream>>>(x, W, xswz, wbf, bpre, out);
    } else {
        heaplin_fallback<<<grid, 256, 0, stream>>>(x, W, bs, out);
    }
}